// Round 7
// baseline (197.111 us; speedup 1.0000x reference)
//
#include <hip/hip_runtime.h>
#include <hip/hip_bf16.h>

// B=2, H=96, W=128, D=64, C=32, F=32, kernel 3x3x3, pad 1 in h/w, depth-shifted.
#define Bn 2
#define Hn 96
#define Wn 128
#define Dn 64
#define Cn 32
#define Fn 32
#define TH 2                 // patch: 2 h-rows
#define TW 8                 // patch: 8 w-cols  -> 16 pixels, one per wave
#define CW (TW + 2)          // 10 staged w-cols
#define NCOLS (4 * CW)       // 4 h-rows x 10 w-cols = 40 columns x 4KB = 160KB LDS

typedef short bf16x8 __attribute__((ext_vector_type(8)));
typedef float f32x4  __attribute__((ext_vector_type(4)));

__device__ __forceinline__ ushort f2bf(float x) {
    __hip_bfloat16 h = __float2bfloat16(x);   // RNE
    return *reinterpret_cast<ushort*>(&h);
}

// Rows are 32 shorts (64B) = 4 slots of 16B. slot' = slot ^ ((r>>1)&3):
// 16 consecutive rows at one slot spread over all 8 bank-quads (2-way = free).
// NOTE: XOR term is invariant under row += 16 -> fragment offsets step by +512 shorts.
__device__ __forceinline__ int swz_off(int r, int slot) {
    return r * 32 + ((slot ^ ((r >> 1) & 3)) << 3);
}

// ---- prep: transpose kernel weights to bf16 kT[27][f][c] in workspace
__global__ void prep_kT(const float* __restrict__ kern, ushort* __restrict__ kT) {
    const int e = blockIdx.x * 256 + threadIdx.x;    // 27*32*32 = 27648
    if (e >= 27 * Cn * Fn) return;
    const int c  = e & 31;
    const int f  = (e >> 5) & 31;
    const int kk = e >> 10;
    kT[e] = f2bf(kern[kk * (Cn * Fn) + c * Fn + f]);
}

__global__ __launch_bounds__(1024, 4) void sconv3d_mfma(
    const float*  __restrict__ img,   // [B,H,W,D,C]
    const int*    __restrict__ bp,    // [B,H,W]
    const float*  __restrict__ kern,  // [3,3,3,C,F] (fp32, for dv path)
    const ushort* __restrict__ kT,    // [27][F][C] bf16
    const float*  __restrict__ dvp,
    float*        __restrict__ out)   // [B,H,W,D,F]
{
    // 40 halo columns, bf16 [col][d 0..63][c], swizzled 16B slots.
    // col j = rh*CW + wc, rh 0..3 <-> image row h0-1+rh.
    __shared__ ushort colS[NCOLS * Dn * Cn];         // 163840 B

    const int blk = blockIdx.x;
    const int wt  = blk % (Wn / TW);
    const int ht  = (blk / (Wn / TW)) % (Hn / TH);
    const int b   = blk / ((Wn / TW) * (Hn / TH));
    const int h0  = ht * TH;
    const int w0  = wt * TW;

    const int tid  = threadIdx.x;
    const int lane = tid & 63;
    const int wave = tid >> 6;                       // 0..15
    const int ph   = wave >> 3;                      // 0..1
    const int pw   = wave & 7;                       // 0..7
    const int h    = h0 + ph;
    const int w    = w0 + pw;

    const int lrow = lane & 15;                      // A row (d within 16) / B f-col
    const int lgrp = lane >> 4;                      // 16B k-slot (c-block)

    const float dv  = *dvp;
    const int   bpc = bp[(b * Hn + h) * Wn + w];

    // ---- per-wave tap shifts & validity
    int  sh[9];
    bool tv[9];
#pragma unroll
    for (int kh = 0; kh < 3; ++kh)
#pragma unroll
        for (int kw = 0; kw < 3; ++kw) {
            const int hh = h - 1 + kh;
            const int ww = w - 1 + kw;
            const bool v = (hh >= 0) && (hh < Hn) && (ww >= 0) && (ww < Wn);
            tv[kh * 3 + kw] = v;
            sh[kh * 3 + kw] = v ? (bpc - bp[(b * Hn + hh) * Wn + ww]) : 0;
        }

    // staging decomposition: per phase 20 cols x 512 ushort4-slots, 10 per thread.
    // e = it*1024 + tid: jl = e>>9 (0..19), sl = e&511.

    // ---- issue PHASE-2 loads first (rows h0+1, h0+2): latency hides under phase 1
    float4 pv[10];
#pragma unroll
    for (int it = 0; it < 10; ++it) {
        const int e  = it * 1024 + tid;
        const int jl = e >> 9;
        const int sl = e & 511;
        const int hh = h0 + 1 + (jl >= CW ? 1 : 0);
        const int ww = w0 - 1 + (jl % CW);
        const bool v = (hh < Hn) && (ww >= 0) && (ww < Wn);
        pv[it] = v ? *(const float4*)(img +
                      (size_t)((b * Hn + hh) * Wn + ww) * (Dn * Cn) + sl * 4)
                   : make_float4(0.f, 0.f, 0.f, 0.f);
    }

    // ---- PHASE-1 stage (rows h0-1, h0 -> cols 0..19)
#pragma unroll
    for (int it = 0; it < 10; ++it) {
        const int e  = it * 1024 + tid;
        const int jl = e >> 9;
        const int sl = e & 511;
        const int hh = h0 - 1 + (jl >= CW ? 1 : 0);
        const int ww = w0 - 1 + (jl % CW);
        if (hh >= 0 && ww >= 0 && ww < Wn) {
            const float4 v = *(const float4*)(img +
                (size_t)((b * Hn + hh) * Wn + ww) * (Dn * Cn) + sl * 4);
            ushort4 u;
            u.x = f2bf(v.x); u.y = f2bf(v.y); u.z = f2bf(v.z); u.w = f2bf(v.w);
            *(ushort4*)&colS[jl * (Dn * Cn)
                             + swz_off(sl >> 3, (sl >> 1) & 3) + (sl & 1) * 4] = u;
        }
    }
    __syncthreads();                                 // B1: phase-1 cols ready

    // ---- PHASE-2 write (cols 20..39; disjoint from kh=0's reads, no WAR)
#pragma unroll
    for (int it = 0; it < 10; ++it) {
        const int e  = it * 1024 + tid;
        const int jl = e >> 9;
        const int sl = e & 511;
        ushort4 u;
        u.x = f2bf(pv[it].x); u.y = f2bf(pv[it].y);
        u.z = f2bf(pv[it].z); u.w = f2bf(pv[it].w);
        *(ushort4*)&colS[(20 + jl) * (Dn * Cn)
                         + swz_off(sl >> 3, (sl >> 1) & 3) + (sl & 1) * 4] = u;
    }

    f32x4 acc[4][2];
#pragma unroll
    for (int i = 0; i < 4; ++i)
#pragma unroll
        for (int j = 0; j < 2; ++j) acc[i][j] = (f32x4)0.f;

    // ---- per-kh tap-group compute. |shift|<=16 => dt=1 (rows 16..47) and
    // dt=2 (+16) are ALWAYS depth-valid: no clamp, offsets o1 / o1+512.
    auto compute_kh = [&](int kh) {
#pragma unroll
        for (int kw = 0; kw < 3; ++kw) {
            if (!tv[kh * 3 + kw]) continue;          // sp_valid false -> dv(=0)
            const int s = sh[kh * 3 + kw];
            const ushort* colp = &colS[((ph + kh) * CW + (pw + kw)) * (Dn * Cn)];
            const int kkb = (kh * 3 + kw) * 3;
            // hoist the 6 B-fragments for this tap group (deep VMEM MLP vs kT)
            bf16x8 bfr[3][2];
#pragma unroll
            for (int kd = 0; kd < 3; ++kd) {
                bfr[kd][0] = *(const bf16x8*)&kT[((kkb + kd) * Fn + lrow)      * Cn + lgrp * 8];
                bfr[kd][1] = *(const bf16x8*)&kT[((kkb + kd) * Fn + lrow + 16) * Cn + lgrp * 8];
            }
            __builtin_amdgcn_s_setprio(1);
#pragma unroll
            for (int kd = 0; kd < 3; ++kd) {
                const int i1 = 16 + lrow + s + kd - 1;   // in [0,47] always
                const int o1 = swz_off(i1, lgrp);
                // dt=1, dt=2: unconditional
                const bf16x8 a1 = *(const bf16x8*)&colp[o1];
                acc[1][0] = __builtin_amdgcn_mfma_f32_16x16x32_bf16(a1, bfr[kd][0], acc[1][0], 0, 0, 0);
                acc[1][1] = __builtin_amdgcn_mfma_f32_16x16x32_bf16(a1, bfr[kd][1], acc[1][1], 0, 0, 0);
                const bf16x8 a2 = *(const bf16x8*)&colp[o1 + 512];
                acc[2][0] = __builtin_amdgcn_mfma_f32_16x16x32_bf16(a2, bfr[kd][0], acc[2][0], 0, 0, 0);
                acc[2][1] = __builtin_amdgcn_mfma_f32_16x16x32_bf16(a2, bfr[kd][1], acc[2][1], 0, 0, 0);
                // dt=0: valid iff i1>=16
                {
                    const bool v = (i1 >= 16);
                    bf16x8 a0 = *(const bf16x8*)&colp[v ? o1 - 512 : o1];
                    if (!v) a0 = (bf16x8)0;
                    acc[0][0] = __builtin_amdgcn_mfma_f32_16x16x32_bf16(a0, bfr[kd][0], acc[0][0], 0, 0, 0);
                    acc[0][1] = __builtin_amdgcn_mfma_f32_16x16x32_bf16(a0, bfr[kd][1], acc[0][1], 0, 0, 0);
                }
                // dt=3: valid iff i1<=31
                {
                    const bool v = (i1 <= 31);
                    bf16x8 a3 = *(const bf16x8*)&colp[v ? o1 + 1024 : o1];
                    if (!v) a3 = (bf16x8)0;
                    acc[3][0] = __builtin_amdgcn_mfma_f32_16x16x32_bf16(a3, bfr[kd][0], acc[3][0], 0, 0, 0);
                    acc[3][1] = __builtin_amdgcn_mfma_f32_16x16x32_bf16(a3, bfr[kd][1], acc[3][1], 0, 0, 0);
                }
            }
            __builtin_amdgcn_s_setprio(0);
        }
    };

    compute_kh(0);                                   // needs rows h0-1,h0 only
    __syncthreads();                                 // B2: phase-2 cols ready
    compute_kh(1);
    compute_kh(2);

    // ---- dv != 0 correction (dead for this benchmark; keeps semantics general)
    if (dv != 0.0f) {
#pragma unroll
        for (int kh = 0; kh < 3; ++kh)
#pragma unroll
            for (int kw = 0; kw < 3; ++kw) {
                const bool sp = tv[kh * 3 + kw];
                const int  s  = sh[kh * 3 + kw];
                for (int kd = 0; kd < 3; ++kd) {
                    float ks0 = 0.f, ks1 = 0.f;
                    for (int c = 0; c < Cn; ++c) {
                        const float* kp = kern + (size_t)(((kh * 3 + kw) * 3 + kd) * Cn + c) * Fn;
                        ks0 += kp[lrow];
                        ks1 += kp[16 + lrow];
                    }
                    for (int dt = 0; dt < 4; ++dt)
                        for (int j = 0; j < 4; ++j) {
                            const int d   = dt * 16 + lgrp * 4 + j;
                            const int idx = d + s + kd - 1;
                            const bool valid = sp && (idx >= 0) && (idx < Dn);
                            if (!valid) { acc[dt][0][j] += dv * ks0; acc[dt][1][j] += dv * ks1; }
                        }
                }
            }
    }

    // ---- epilogue: D lane l reg j -> d = dt*16 + lgrp*4 + j, f = ft*16 + lrow
    const size_t pixbase = ((size_t)(b * Hn + h) * Wn + w) * (Dn * Fn);
#pragma unroll
    for (int dt = 0; dt < 4; ++dt)
#pragma unroll
        for (int ft = 0; ft < 2; ++ft)
#pragma unroll
            for (int j = 0; j < 4; ++j) {
                const int d = dt * 16 + lgrp * 4 + j;
                const int f = ft * 16 + lrow;
                out[pixbase + d * Fn + f] = acc[dt][ft][j];
            }
}

extern "C" void kernel_launch(void* const* d_in, const int* in_sizes, int n_in,
                              void* d_out, int out_size, void* d_ws, size_t ws_size,
                              hipStream_t stream) {
    const float* img  = (const float*)d_in[0];
    const int*   bp   = (const int*)d_in[1];
    const float* kern = (const float*)d_in[2];
    const float* dvp  = (const float*)d_in[3];
    float* out = (float*)d_out;
    ushort* kT = (ushort*)d_ws;                      // 27*32*32*2 = 55296 B

    hipLaunchKernelGGL(prep_kT, dim3(108), dim3(256), 0, stream, kern, kT);

    const int nblk = Bn * (Hn / TH) * (Wn / TW);     // 2*48*16 = 1536
    hipLaunchKernelGGL(sconv3d_mfma, dim3(nblk), dim3(1024), 0, stream,
                       img, bp, kern, kT, dvp, out);
}